// Round 1
// baseline (205.682 us; speedup 1.0000x reference)
//
#include <hip/hip_runtime.h>
#include <stdint.h>

typedef unsigned short u16;
typedef __attribute__((ext_vector_type(8))) short short8;   // 8 bf16 (4 VGPRs) — MFMA A/B frag
typedef __attribute__((ext_vector_type(4))) float float4v;  // MFMA C/D frag

__device__ __forceinline__ u16 f2bf(float f) {
    union { float f; uint32_t u; } v; v.f = f;
    uint32_t r = v.u + 0x7fffu + ((v.u >> 16) & 1u);  // RNE
    return (u16)(r >> 16);
}

__device__ __forceinline__ void gload16(const u16* g, u16* l) {
    __builtin_amdgcn_global_load_lds(
        (const __attribute__((address_space(1))) void*)g,
        (__attribute__((address_space(3))) void*)l, 16, 0, 0);
}

// ---------------- x -> bf16 ----------------
__global__ void cvt_f32_bf16(const float* __restrict__ x, u16* __restrict__ y) {
    int i = (blockIdx.x * 256 + threadIdx.x) * 4;
    float4 v = *(const float4*)(x + i);
    union { u16 s[4]; uint64_t q; } o;
    o.s[0] = f2bf(v.x); o.s[1] = f2bf(v.y); o.s[2] = f2bf(v.z); o.s[3] = f2bf(v.w);
    *(uint64_t*)(y + i) = o.q;
}

// ------------- merged weight, transposed to [N,K] bf16 -------------
// W: [E=8, K, N] f32.  Wt[o*K + i] = bf16( (sum_e w_e * W[e,i,o]) / sum_e w_e )
// grid (N/32, K/32), block 256 (= 32 x 8), LDS 32x33 transpose tile.
__global__ void merge_w(const float* __restrict__ W, const float* __restrict__ wts,
                        u16* __restrict__ Wt, int K, int N) {
    __shared__ float tile[32][33];
    float wn[8]; float s = 0.f;
    #pragma unroll
    for (int e = 0; e < 8; ++e) { wn[e] = wts[e]; s += wn[e]; }
    float inv = 1.0f / s;
    int o0 = blockIdx.x * 32, i0 = blockIdx.y * 32;
    int tx = threadIdx.x & 31, ty = threadIdx.x >> 5;
    #pragma unroll
    for (int s4 = 0; s4 < 4; ++s4) {
        int il = ty + s4 * 8;
        float acc = 0.f;
        #pragma unroll
        for (int e = 0; e < 8; ++e)
            acc += wn[e] * W[(size_t)e * K * N + (size_t)(i0 + il) * N + o0 + tx];
        tile[il][tx] = acc * inv;
    }
    __syncthreads();
    #pragma unroll
    for (int s4 = 0; s4 < 4; ++s4) {
        int ol = ty + s4 * 8;
        Wt[(size_t)(o0 + ol) * K + i0 + tx] = f2bf(tile[tx][ol]);
    }
}

// ------------- merged bias (all 3 layers in one launch) -------------
__global__ void merge_bias(const float* __restrict__ wts,
                           const float* __restrict__ b0, const float* __restrict__ b1,
                           const float* __restrict__ b2, float* __restrict__ bm) {
    int t = blockIdx.x * 256 + threadIdx.x;
    if (t >= 2560) return;
    float wn[8]; float s = 0.f;
    #pragma unroll
    for (int e = 0; e < 8; ++e) { wn[e] = wts[e]; s += wn[e]; }
    float inv = 1.0f / s;
    const float* b; int o, stride;
    if (t < 1024)      { b = b0; o = t;        stride = 1024; }
    else if (t < 2048) { b = b1; o = t - 1024; stride = 1024; }
    else               { b = b2; o = t - 2048; stride = 512;  }
    float acc = 0.f;
    #pragma unroll
    for (int e = 0; e < 8; ++e) acc += wn[e] * b[e * stride + o];
    bm[t] = acc * inv;
}

// ------------- GEMM + bias + PReLU -------------
// A [M,K] bf16 row-major, Bt [N,K] bf16 (B transposed), out [M,N].
// 128x128 tile, BK=64, 256 thr = 4 waves in 2x2, each wave 64x64 = 4x4 MFMA 16x16x32.
// LDS chunk swizzle: chunk position p holds global k-chunk (p ^ (row&7)) — applied on
// the GLOBAL source address at staging (LDS side must stay lane-contiguous for
// global_load_lds) and on the ds_read_b128 addresses, making frag reads 2-way (free).
template <bool OUT_F32>
__global__ __launch_bounds__(256) void gemm_bias_prelu(
    const u16* __restrict__ A, const u16* __restrict__ Bt,
    const float* __restrict__ bias, const float* __restrict__ alpha,
    void* __restrict__ outp, int M, int N, int K) {
    __shared__ __align__(16) u16 As[128 * 64];
    __shared__ __align__(16) u16 Bs[128 * 64];
    const int tid = threadIdx.x;
    const int bn = blockIdx.x, bm = blockIdx.y;

    // staging: thread t, issue it -> LDS chunk (it*256 + t); row r = chunk/8, pos p = chunk%8
    const int r0 = tid >> 3;           // 0..31 (row within issue group; +32 per issue)
    const int p  = tid & 7;
    const int c  = p ^ (r0 & 7);       // global k-chunk to fetch ((r&7) invariant: +32 ≡ 0 mod 8)
    const u16* Ag = A  + (size_t)(bm * 128 + r0) * K + c * 8;
    const u16* Bg = Bt + (size_t)(bn * 128 + r0) * K + c * 8;
    u16* Al = As + tid * 8;
    u16* Bl = Bs + tid * 8;

    const int lane = tid & 63, w = tid >> 6;
    const int wm = (w >> 1) * 64, wn = (w & 1) * 64;
    const int l16 = lane & 15, quad = lane >> 4;
    const int xr = l16 & 7;            // row&7 for all fragment rows (wm, mi*16 ≡ 0 mod 8)
    const short8* As8 = (const short8*)As;
    const short8* Bs8 = (const short8*)Bs;

    float4v acc[4][4] = {};

    const int nk = K >> 6;
    for (int kt = 0; kt < nk; ++kt) {
        #pragma unroll
        for (int it = 0; it < 4; ++it) {
            gload16(Ag + (size_t)(it * 32) * K, Al + it * 2048);
            gload16(Bg + (size_t)(it * 32) * K, Bl + it * 2048);
        }
        __syncthreads();   // compiler drains vmcnt here (global_load_lds complete)
        #pragma unroll
        for (int kk = 0; kk < 2; ++kk) {
            const int cb = kk * 4;
            short8 af[4], bf[4];
            #pragma unroll
            for (int mi = 0; mi < 4; ++mi)
                af[mi] = As8[(wm + mi * 16 + l16) * 8 + ((cb + quad) ^ xr)];
            #pragma unroll
            for (int ni = 0; ni < 4; ++ni)
                bf[ni] = Bs8[(wn + ni * 16 + l16) * 8 + ((cb + quad) ^ xr)];
            #pragma unroll
            for (int mi = 0; mi < 4; ++mi)
                #pragma unroll
                for (int ni = 0; ni < 4; ++ni)
                    acc[mi][ni] = __builtin_amdgcn_mfma_f32_16x16x32_bf16(
                        af[mi], bf[ni], acc[mi][ni], 0, 0, 0);
        }
        if (kt + 1 < nk) __syncthreads();  // protect LDS before next staging
        Ag += 64; Bg += 64;
    }

    // epilogue: C/D layout col=lane&15, row=quad*4+reg  [m89/m91 verified]
    const int cbase = bn * 128 + wn + l16;
    float bv[4], av[4];
    #pragma unroll
    for (int ni = 0; ni < 4; ++ni) { bv[ni] = bias[cbase + ni * 16]; av[ni] = alpha[cbase + ni * 16]; }
    const int rbase = bm * 128 + wm + quad * 4;
    #pragma unroll
    for (int mi = 0; mi < 4; ++mi) {
        #pragma unroll
        for (int reg = 0; reg < 4; ++reg) {
            int r = rbase + mi * 16 + reg;
            #pragma unroll
            for (int ni = 0; ni < 4; ++ni) {
                float v = acc[mi][ni][reg] + bv[ni];
                v = v >= 0.f ? v : av[ni] * v;
                size_t idx = (size_t)r * N + cbase + ni * 16;
                if (OUT_F32) ((float*)outp)[idx] = v;
                else         ((u16*)outp)[idx] = f2bf(v);
            }
        }
    }
}

extern "C" void kernel_launch(void* const* d_in, const int* in_sizes, int n_in,
                              void* d_out, int out_size, void* d_ws, size_t ws_size,
                              hipStream_t stream) {
    const float* x   = (const float*)d_in[0];
    const float* wts = (const float*)d_in[1];
    const float* W0  = (const float*)d_in[2];
    const float* b0  = (const float*)d_in[3];
    const float* a0  = (const float*)d_in[4];
    const float* W1  = (const float*)d_in[5];
    const float* b1  = (const float*)d_in[6];
    const float* a1  = (const float*)d_in[7];
    const float* W2  = (const float*)d_in[8];
    const float* b2  = (const float*)d_in[9];
    const float* a2  = (const float*)d_in[10];
    float* out = (float*)d_out;

    char* ws = (char*)d_ws;
    u16*   xbf  = (u16*)ws;  ws += (size_t)8192 * 512 * 2;
    u16*   act1 = (u16*)ws;  ws += (size_t)8192 * 1024 * 2;
    u16*   act2 = (u16*)ws;  ws += (size_t)8192 * 1024 * 2;
    u16*   W0t  = (u16*)ws;  ws += (size_t)1024 * 512 * 2;
    u16*   W1t  = (u16*)ws;  ws += (size_t)1024 * 1024 * 2;
    u16*   W2t  = (u16*)ws;  ws += (size_t)512 * 1024 * 2;
    float* bm   = (float*)ws;  // 2560 floats

    // prep (independent)
    cvt_f32_bf16<<<4096, 256, 0, stream>>>(x, xbf);                       // 8192*512/4/256
    merge_w<<<dim3(32, 16), 256, 0, stream>>>(W0, wts, W0t, 512, 1024);
    merge_w<<<dim3(32, 32), 256, 0, stream>>>(W1, wts, W1t, 1024, 1024);
    merge_w<<<dim3(16, 32), 256, 0, stream>>>(W2, wts, W2t, 1024, 512);
    merge_bias<<<10, 256, 0, stream>>>(wts, b0, b1, b2, bm);

    // layers (sequential): grid (N/128, M/128)
    gemm_bias_prelu<false><<<dim3(8, 64), 256, 0, stream>>>(xbf,  W0t, bm,        a0, act1, 8192, 1024, 512);
    gemm_bias_prelu<false><<<dim3(8, 64), 256, 0, stream>>>(act1, W1t, bm + 1024, a1, act2, 8192, 1024, 1024);
    gemm_bias_prelu<true ><<<dim3(4, 64), 256, 0, stream>>>(act2, W2t, bm + 2048, a2, out,  8192, 512, 1024);
}

// Round 2
// 196.449 us; speedup vs baseline: 1.0470x; 1.0470x over previous
//
#include <hip/hip_runtime.h>
#include <stdint.h>

typedef unsigned short u16;
typedef __attribute__((ext_vector_type(8))) short short8;   // 8 bf16 (4 VGPRs) — MFMA A/B frag
typedef __attribute__((ext_vector_type(4))) float float4v;  // MFMA C/D frag

__device__ __forceinline__ u16 f2bf(float f) {
    union { float f; uint32_t u; } v; v.f = f;
    uint32_t r = v.u + 0x7fffu + ((v.u >> 16) & 1u);  // RNE
    return (u16)(r >> 16);
}

__device__ __forceinline__ void gload16(const u16* g, u16* l) {
    __builtin_amdgcn_global_load_lds(
        (const __attribute__((address_space(1))) void*)g,
        (__attribute__((address_space(3))) void*)l, 16, 0, 0);
}

// ---------------- fused prep: x->bf16, 3x weight merge+transpose, bias merge ----
// block ranges: [0,4096) cvt | [4096,4608) W0 | [4608,5632) W1 | [5632,6144) W2
//               [6144,6154) bias
// merge: W [E=8,K,N] f32 -> Wt [N,K] bf16 with Wt[o*K+i] = sum_e wn_e W[e,i,o]
__global__ __launch_bounds__(256) void prep_fused(
    const float* __restrict__ x, u16* __restrict__ xbf,
    const float* __restrict__ wts,
    const float* __restrict__ W0, const float* __restrict__ W1, const float* __restrict__ W2,
    u16* __restrict__ W0t, u16* __restrict__ W1t, u16* __restrict__ W2t,
    const float* __restrict__ b0, const float* __restrict__ b1, const float* __restrict__ b2,
    float* __restrict__ bm) {
    __shared__ float tile[32][33];
    const int b = blockIdx.x, tid = threadIdx.x;

    if (b < 4096) {                       // ---- x -> bf16, 4 elem/thread ----
        int i = (b * 256 + tid) * 4;
        float4 v = *(const float4*)(x + i);
        union { u16 s[4]; uint64_t q; } o;
        o.s[0] = f2bf(v.x); o.s[1] = f2bf(v.y); o.s[2] = f2bf(v.z); o.s[3] = f2bf(v.w);
        *(uint64_t*)(xbf + i) = o.q;
        return;
    }

    float wn[8]; float s = 0.f;
    #pragma unroll
    for (int e = 0; e < 8; ++e) { wn[e] = wts[e]; s += wn[e]; }
    const float inv = 1.0f / s;

    if (b < 6144) {                       // ---- weight merge + transpose ----
        const float* W; u16* Wt; int K, N, lb;
        if (b < 4608)      { W = W0; Wt = W0t; K = 512;  N = 1024; lb = b - 4096; }
        else if (b < 5632) { W = W1; Wt = W1t; K = 1024; N = 1024; lb = b - 4608; }
        else               { W = W2; Wt = W2t; K = 1024; N = 512;  lb = b - 5632; }
        const int ntiles = N >> 5;
        const int o0 = (lb % ntiles) * 32, i0 = (lb / ntiles) * 32;
        const int tx = tid & 31, ty = tid >> 5;
        #pragma unroll
        for (int s4 = 0; s4 < 4; ++s4) {
            int il = ty + s4 * 8;
            float acc = 0.f;
            #pragma unroll
            for (int e = 0; e < 8; ++e)
                acc += wn[e] * W[(size_t)e * K * N + (size_t)(i0 + il) * N + o0 + tx];
            tile[il][tx] = acc * inv;
        }
        __syncthreads();
        #pragma unroll
        for (int s4 = 0; s4 < 4; ++s4) {
            int ol = ty + s4 * 8;
            Wt[(size_t)(o0 + ol) * K + i0 + tx] = f2bf(tile[tx][ol]);
        }
        return;
    }

    // ---- bias merge: 2560 outputs ----
    int t = (b - 6144) * 256 + tid;
    if (t >= 2560) return;
    const float* bp; int o, stride;
    if (t < 1024)      { bp = b0; o = t;        stride = 1024; }
    else if (t < 2048) { bp = b1; o = t - 1024; stride = 1024; }
    else               { bp = b2; o = t - 2048; stride = 512;  }
    float acc = 0.f;
    #pragma unroll
    for (int e = 0; e < 8; ++e) acc += wn[e] * bp[e * stride + o];
    bm[t] = acc * inv;
}

// ------------- GEMM + bias + PReLU -------------
// A [M,K] bf16 row-major, Bt [N,K] bf16 (B^T), out [M,N].
// 128(M)x64(N) block tile, BK=64, 256 thr = 4 waves in 2(M)x2(N);
// wave tile 64x32 = 4x2 MFMA 16x16x32.
// XOR chunk swizzle applied at the GLOBAL source address during staging (LDS side
// stays lane-contiguous per global_load_lds constraint) and mirrored on ds_read
// addresses -> fragment reads are 2-way (free, m136).
template <bool OUT_F32>
__global__ __launch_bounds__(256, 4) void gemm_bias_prelu(
    const u16* __restrict__ A, const u16* __restrict__ Bt,
    const float* __restrict__ bias, const float* __restrict__ alpha,
    void* __restrict__ outp, int M, int N, int K) {
    __shared__ __align__(16) u16 As[128 * 64];   // 16 KB
    __shared__ __align__(16) u16 Bs[64 * 64];    //  8 KB
    const int tid = threadIdx.x;
    const int bn = blockIdx.x, bm = blockIdx.y;

    // staging: thread t, issue it -> LDS chunk (it*256 + t); row r = chunk/8, pos p = chunk%8
    const int r0 = tid >> 3;           // 0..31 (+32 per issue; (r&7) invariant)
    const int p  = tid & 7;
    const int c  = p ^ (r0 & 7);       // global k-chunk fetched into LDS pos p
    const u16* Ag = A  + (size_t)(bm * 128 + r0) * K + c * 8;
    const u16* Bg = Bt + (size_t)(bn * 64  + r0) * K + c * 8;
    u16* Al = As + tid * 8;
    u16* Bl = Bs + tid * 8;

    const int lane = tid & 63, w = tid >> 6;
    const int wm = (w >> 1) * 64, wncol = (w & 1) * 32;
    const int l16 = lane & 15, quad = lane >> 4;
    const int xr = l16 & 7;            // (row&7) of every fragment row (offsets ≡ 0 mod 8)
    const short8* As8 = (const short8*)As;
    const short8* Bs8 = (const short8*)Bs;

    float4v acc[4][2] = {};

    const int nk = K >> 6;
    for (int kt = 0; kt < nk; ++kt) {
        #pragma unroll
        for (int it = 0; it < 4; ++it)
            gload16(Ag + (size_t)(it * 32) * K, Al + it * 2048);
        #pragma unroll
        for (int it = 0; it < 2; ++it)
            gload16(Bg + (size_t)(it * 32) * K, Bl + it * 2048);
        __syncthreads();
        #pragma unroll
        for (int kk = 0; kk < 2; ++kk) {
            const int cb = kk * 4;
            short8 af[4], bf[2];
            #pragma unroll
            for (int mi = 0; mi < 4; ++mi)
                af[mi] = As8[(wm + mi * 16 + l16) * 8 + ((cb + quad) ^ xr)];
            #pragma unroll
            for (int ni = 0; ni < 2; ++ni)
                bf[ni] = Bs8[(wncol + ni * 16 + l16) * 8 + ((cb + quad) ^ xr)];
            #pragma unroll
            for (int mi = 0; mi < 4; ++mi)
                #pragma unroll
                for (int ni = 0; ni < 2; ++ni)
                    acc[mi][ni] = __builtin_amdgcn_mfma_f32_16x16x32_bf16(
                        af[mi], bf[ni], acc[mi][ni], 0, 0, 0);
        }
        if (kt + 1 < nk) __syncthreads();
        Ag += 64; Bg += 64;
    }

    // epilogue: C/D layout col=lane&15, row=quad*4+reg  [m89/m91]
    const int cbase = bn * 64 + wncol + l16;
    float bv[2], av[2];
    #pragma unroll
    for (int ni = 0; ni < 2; ++ni) { bv[ni] = bias[cbase + ni * 16]; av[ni] = alpha[cbase + ni * 16]; }
    const int rbase = bm * 128 + wm + quad * 4;
    #pragma unroll
    for (int mi = 0; mi < 4; ++mi) {
        #pragma unroll
        for (int reg = 0; reg < 4; ++reg) {
            int r = rbase + mi * 16 + reg;
            #pragma unroll
            for (int ni = 0; ni < 2; ++ni) {
                float v = acc[mi][ni][reg] + bv[ni];
                v = v >= 0.f ? v : av[ni] * v;
                size_t idx = (size_t)r * N + cbase + ni * 16;
                if (OUT_F32) ((float*)outp)[idx] = v;
                else         ((u16*)outp)[idx] = f2bf(v);
            }
        }
    }
}

extern "C" void kernel_launch(void* const* d_in, const int* in_sizes, int n_in,
                              void* d_out, int out_size, void* d_ws, size_t ws_size,
                              hipStream_t stream) {
    const float* x   = (const float*)d_in[0];
    const float* wts = (const float*)d_in[1];
    const float* W0  = (const float*)d_in[2];
    const float* b0  = (const float*)d_in[3];
    const float* a0  = (const float*)d_in[4];
    const float* W1  = (const float*)d_in[5];
    const float* b1  = (const float*)d_in[6];
    const float* a1  = (const float*)d_in[7];
    const float* W2  = (const float*)d_in[8];
    const float* b2  = (const float*)d_in[9];
    const float* a2  = (const float*)d_in[10];
    float* out = (float*)d_out;

    char* ws = (char*)d_ws;
    u16*   xbf  = (u16*)ws;  ws += (size_t)8192 * 512 * 2;
    u16*   act1 = (u16*)ws;  ws += (size_t)8192 * 1024 * 2;
    u16*   act2 = (u16*)ws;  ws += (size_t)8192 * 1024 * 2;
    u16*   W0t  = (u16*)ws;  ws += (size_t)1024 * 512 * 2;
    u16*   W1t  = (u16*)ws;  ws += (size_t)1024 * 1024 * 2;
    u16*   W2t  = (u16*)ws;  ws += (size_t)512 * 1024 * 2;
    float* bm   = (float*)ws;  // 2560 floats

    // single fused prep launch: 4096 cvt + 512 + 1024 + 512 merge + 10 bias = 6154 blocks
    prep_fused<<<6154, 256, 0, stream>>>(x, xbf, wts, W0, W1, W2, W0t, W1t, W2t,
                                         b0, b1, b2, bm);

    // layers (sequential): grid (N/64, M/128)
    gemm_bias_prelu<false><<<dim3(16, 64), 256, 0, stream>>>(xbf,  W0t, bm,        a0, act1, 8192, 1024, 512);
    gemm_bias_prelu<false><<<dim3(16, 64), 256, 0, stream>>>(act1, W1t, bm + 1024, a1, act2, 8192, 1024, 1024);
    gemm_bias_prelu<true ><<<dim3(8, 64),  256, 0, stream>>>(act2, W2t, bm + 2048, a2, out,  8192, 512, 1024);
}